// Round 5
// baseline (550.631 us; speedup 1.0000x reference)
//
#include <hip/hip_runtime.h>
#include <hip/hip_cooperative_groups.h>

namespace cg = cooperative_groups;

#define BLK 512
#define MAXGRID 512
#define TILE 80   // gemm rows per block-tile

struct Args {
    const float* x; const int* src; const int* dst;
    const float* W1l; const float* b1l; const float* W1r;
    const float* W2l; const float* b2l; const float* W2r;
    float* z;
    unsigned short* Pb; float* Q; float* H;
    float* WT1l; float* WT1r; float* WT2l; float* WT2r;
    int* deg; int* cursor; int* sorted; int* offs; int* partials;
    int N; int E;
};

__device__ __forceinline__ float bf2f(unsigned short u) {
    union { unsigned int i; float f; } c; c.i = ((unsigned int)u) << 16; return c.f;
}
__device__ __forceinline__ unsigned short f2bf(float f) {
    union { float f; unsigned int i; } c; c.f = f;
    return (unsigned short)((c.i + 0x7FFFu + ((c.i >> 16) & 1u)) >> 16);
}

// ======================= cooperative mega-kernel path =======================

// block-wide exclusive scan over BLK values; returns exclusive prefix, total.
__device__ __forceinline__ int block_scan_excl(int v, int tid, int* wsum, int& total) {
    const int lane = tid & 63, w = tid >> 6;
    int s = v;
    #pragma unroll
    for (int off = 1; off < 64; off <<= 1) {
        int t = __shfl_up(s, off, 64);
        if (lane >= off) s += t;
    }
    __syncthreads();               // protect wsum reuse across calls
    if (lane == 63) wsum[w] = s;
    __syncthreads();
    int wbase = 0, tot = 0;
    #pragma unroll
    for (int ww = 0; ww < BLK / 64; ++ww) {
        int t = wsum[ww];
        tot += t;
        if (ww < w) wbase += t;
    }
    total = tot;
    return wbase + s - v;
}

template <int K>
__device__ __forceinline__ void gemm_phase(const float* __restrict__ A,
                                           const float* __restrict__ WTl,
                                           const float* __restrict__ WTr,
                                           unsigned short* __restrict__ Pb,
                                           float* __restrict__ Qo,
                                           float (*As)[65], int tid, int N) {
    const int nTiles = (N + TILE - 1) / TILE;
    for (int t = blockIdx.x; t < nTiles; t += gridDim.x) {
        const int r0 = t * TILE;
        const int tx = tid & 31;   // column pair
        const int ty = tid >> 5;   // 5-row group
        float accl[5][2] = {{0.f}}, accr[5][2] = {{0.f}};
        for (int h = 0; h < K; h += 64) {
            __syncthreads();
            for (int idx = tid; idx < TILE * 16; idx += BLK) {
                const int row = idx >> 4, c4 = idx & 15;
                float4 v = make_float4(0.f, 0.f, 0.f, 0.f);
                if (r0 + row < N)
                    v = *(const float4*)&A[(size_t)(r0 + row) * K + h + c4 * 4];
                As[row][c4 * 4 + 0] = v.x; As[row][c4 * 4 + 1] = v.y;
                As[row][c4 * 4 + 2] = v.z; As[row][c4 * 4 + 3] = v.w;
            }
            __syncthreads();
            #pragma unroll 4
            for (int k = 0; k < 64; ++k) {
                float a[5];
                #pragma unroll
                for (int i = 0; i < 5; ++i) a[i] = As[ty * 5 + i][k];
                const float2 bl = *(const float2*)&WTl[(h + k) * 64 + tx * 2];
                const float2 br = *(const float2*)&WTr[(h + k) * 64 + tx * 2];
                #pragma unroll
                for (int i = 0; i < 5; ++i) {
                    accl[i][0] += a[i] * bl.x; accl[i][1] += a[i] * bl.y;
                    accr[i][0] += a[i] * br.x; accr[i][1] += a[i] * br.y;
                }
            }
        }
        #pragma unroll
        for (int i = 0; i < 5; ++i) {
            const int m = r0 + ty * 5 + i;
            if (m < N) {
                ushort2 pv; pv.x = f2bf(accl[i][0]); pv.y = f2bf(accl[i][1]);
                *(ushort2*)&Pb[(size_t)m * 64 + tx * 2] = pv;
                *(float2*)&Qo[(size_t)m * 64 + tx * 2] =
                    make_float2(accr[i][0], accr[i][1]);
            }
        }
    }
}

__device__ __forceinline__ void agg_phase(const unsigned short* __restrict__ Pb,
                                          const float* __restrict__ Qo,
                                          const float* __restrict__ bias,
                                          const int* __restrict__ offs,
                                          const int* __restrict__ sorted,
                                          float* __restrict__ out,
                                          int relu, int gtid, int nwaves, int N) {
    const int lane = gtid & 63;
    const float bv = bias[lane];
    for (int node = gtid >> 6; node < N; node += nwaves) {
        const int s0 = offs[node], s1 = offs[node + 1];
        float acc = 0.f;
        int e = s0;
        for (; e + 7 < s1; e += 8) {
            int si[8];
            #pragma unroll
            for (int j = 0; j < 8; ++j) si[j] = sorted[e + j];
            float v[8];
            #pragma unroll
            for (int j = 0; j < 8; ++j) v[j] = bf2f(Pb[(size_t)si[j] * 64 + lane]);
            #pragma unroll
            for (int j = 0; j < 8; ++j) acc += v[j];
        }
        for (; e < s1; ++e) acc += bf2f(Pb[(size_t)sorted[e] * 64 + lane]);
        float cnt = (float)(s1 - s0);
        float v = acc * (1.0f / fmaxf(cnt, 1.0f)) + bv + Qo[(size_t)node * 64 + lane];
        if (relu) v = fmaxf(v, 0.f);
        out[(size_t)node * 64 + lane] = v;
    }
}

__global__ __launch_bounds__(BLK, 2) void k_mega(Args a) {
    __shared__ float As[TILE][65];      // 20.8 KB
    __shared__ int s_part[BLK];         // 2 KB
    __shared__ int s_wsum[BLK / 64];
    cg::grid_group grid = cg::this_grid();
    const int tid = threadIdx.x;
    const int gtid = blockIdx.x * BLK + tid;
    const int NT = gridDim.x * BLK;
    const int NW = NT >> 6;

    // P0: zero deg + transpose weights ([64][K] -> [K][64])
    for (int i = gtid; i < a.N; i += NT) a.deg[i] = 0;
    if (gtid < 64 * 128) {
        int j = gtid >> 7, k = gtid & 127;
        a.WT1l[k * 64 + j] = a.W1l[gtid];
        a.WT1r[k * 64 + j] = a.W1r[gtid];
    }
    if (gtid < 64 * 64) {
        int j = gtid >> 6, k = gtid & 63;
        a.WT2l[k * 64 + j] = a.W2l[gtid];
        a.WT2r[k * 64 + j] = a.W2r[gtid];
    }
    grid.sync();

    // P1: gemm1 (x -> Pb,Q) + edge-count histogram (independent)
    gemm_phase<128>(a.x, a.WT1l, a.WT1r, a.Pb, a.Q, As, tid, a.N);
    for (int e = gtid; e < a.E; e += NT) atomicAdd(&a.deg[a.dst[e]], 1);
    grid.sync();

    // P2: per-block exclusive scan of deg (one element/thread; NT >= N)
    {
        int v = (gtid < a.N) ? a.deg[gtid] : 0;
        int tot;
        int ex = block_scan_excl(v, tid, s_wsum, tot);
        if (gtid < a.N) a.offs[gtid] = ex;
        if (tid == 0) a.partials[blockIdx.x] = tot;
    }
    grid.sync();

    // P3: every block redundantly scans partials[0..gridDim) (saves a sync)
    {
        int pv = (tid < (int)gridDim.x) ? a.partials[tid] : 0;
        int tot;
        int ex = block_scan_excl(pv, tid, s_wsum, tot);
        s_part[tid] = ex;
        __syncthreads();
        int base = s_part[blockIdx.x];
        if (gtid < a.N) {
            int o = a.offs[gtid] + base;
            a.offs[gtid] = o;
            a.cursor[gtid] = o;
        }
        if (gtid == 0) a.offs[a.N] = a.E;
    }
    grid.sync();

    // P4: scatter edges into CSR order
    for (int e = gtid; e < a.E; e += NT) {
        int p = atomicAdd(&a.cursor[a.dst[e]], 1);
        a.sorted[p] = a.src[e];
    }
    grid.sync();

    // P5: agg1 -> H (ReLU)
    agg_phase(a.Pb, a.Q, a.b1l, a.offs, a.sorted, a.H, 1, gtid, NW, a.N);
    grid.sync();

    // P6: gemm2 (H -> Pb,Q)
    gemm_phase<64>(a.H, a.WT2l, a.WT2r, a.Pb, a.Q, As, tid, a.N);
    grid.sync();

    // P7: agg2 -> z
    agg_phase(a.Pb, a.Q, a.b2l, a.offs, a.sorted, a.z, 0, gtid, NW, a.N);
}

// ========================= multi-kernel fallback path =======================

__global__ __launch_bounds__(256) void k_count(const int* __restrict__ dst,
                                               int* __restrict__ deg, int E) {
    int e = blockIdx.x * 256 + threadIdx.x;
    if (e < E) atomicAdd(&deg[dst[e]], 1);
}

__global__ __launch_bounds__(256) void k_scan_local(const int* __restrict__ deg,
                                                    int* __restrict__ offs,
                                                    int* __restrict__ partials, int n) {
    __shared__ int wsum[4];
    const int tid = threadIdx.x;
    const int i = blockIdx.x * 256 + tid;
    const int lane = tid & 63, w = tid >> 6;
    int v = (i < n) ? deg[i] : 0;
    int s = v;
    #pragma unroll
    for (int off = 1; off < 64; off <<= 1) {
        int t = __shfl_up(s, off, 64);
        if (lane >= off) s += t;
    }
    if (lane == 63) wsum[w] = s;
    __syncthreads();
    int wbase = 0;
    #pragma unroll
    for (int ww = 0; ww < 3; ++ww) wbase += (ww < w) ? wsum[ww] : 0;
    if (i < n) offs[i] = wbase + s - v;
    if (tid == 255) partials[blockIdx.x] = wbase + s;
}

__global__ __launch_bounds__(256) void k_scan_partials(int* __restrict__ partials,
                                                       int* __restrict__ total, int B) {
    __shared__ int wsum[4];
    const int tid = threadIdx.x;
    const int lane = tid & 63, w = tid >> 6;
    int v = (tid < B) ? partials[tid] : 0;
    int s = v;
    #pragma unroll
    for (int off = 1; off < 64; off <<= 1) {
        int t = __shfl_up(s, off, 64);
        if (lane >= off) s += t;
    }
    if (lane == 63) wsum[w] = s;
    __syncthreads();
    int wbase = 0;
    #pragma unroll
    for (int ww = 0; ww < 3; ++ww) wbase += (ww < w) ? wsum[ww] : 0;
    if (tid < B) partials[tid] = wbase + s - v;
    if (tid == 255) *total = wbase + s;
}

__global__ __launch_bounds__(256) void k_scan_add(const int* __restrict__ partials,
                                                  int* __restrict__ offs,
                                                  int* __restrict__ cursor, int n) {
    int i = blockIdx.x * 256 + threadIdx.x;
    if (i < n) {
        int o = offs[i] + partials[blockIdx.x];
        offs[i] = o;
        cursor[i] = o;
    }
}

__global__ __launch_bounds__(256) void k_scatter(const int* __restrict__ src,
                                                 const int* __restrict__ dst,
                                                 int* __restrict__ cursor,
                                                 int* __restrict__ sorted_src, int E) {
    int e = blockIdx.x * 256 + threadIdx.x;
    if (e < E) {
        int p = atomicAdd(&cursor[dst[e]], 1);
        sorted_src[p] = src[e];
    }
}

__global__ __launch_bounds__(256) void k_transpose(
    const float* __restrict__ W1l, const float* __restrict__ W1r,
    const float* __restrict__ W2l, const float* __restrict__ W2r,
    float* __restrict__ WT1l, float* __restrict__ WT1r,
    float* __restrict__ WT2l, float* __restrict__ WT2r) {
    int tid = blockIdx.x * 256 + threadIdx.x;
    if (tid < 64 * 128) {
        int j = tid >> 7, k = tid & 127;
        WT1l[k * 64 + j] = W1l[tid];
        WT1r[k * 64 + j] = W1r[tid];
    }
    if (tid < 64 * 64) {
        int j = tid >> 6, k = tid & 63;
        WT2l[k * 64 + j] = W2l[tid];
        WT2r[k * 64 + j] = W2r[tid];
    }
}

template <int K>
__global__ __launch_bounds__(256) void k_gemm_dual(
    const float* __restrict__ A, const float* __restrict__ WTl,
    const float* __restrict__ WTr, unsigned short* __restrict__ Pb,
    float* __restrict__ Q) {
    __shared__ float As[64][K + 1];
    const int tid = threadIdx.x;
    const int bm  = blockIdx.x * 64;
    for (int idx = tid; idx < 64 * (K / 4); idx += 256) {
        int row = idx / (K / 4), kq = idx % (K / 4);
        const float4 v = ((const float4*)A)[(size_t)(bm + row) * (K / 4) + kq];
        As[row][kq * 4 + 0] = v.x; As[row][kq * 4 + 1] = v.y;
        As[row][kq * 4 + 2] = v.z; As[row][kq * 4 + 3] = v.w;
    }
    __syncthreads();
    const int tx = tid & 15, ty = tid >> 4;
    const int n0 = ty * 4;
    float accl[4][4] = {}, accr[4][4] = {};
    #pragma unroll 8
    for (int k = 0; k < K; ++k) {
        float a[4];
        #pragma unroll
        for (int i = 0; i < 4; ++i) a[i] = As[n0 + i][k];
        const float4 blv = ((const float4*)WTl)[k * 16 + tx];
        const float4 brv = ((const float4*)WTr)[k * 16 + tx];
        const float bl[4] = {blv.x, blv.y, blv.z, blv.w};
        const float br[4] = {brv.x, brv.y, brv.z, brv.w};
        #pragma unroll
        for (int i = 0; i < 4; ++i) {
            #pragma unroll
            for (int j = 0; j < 4; ++j) {
                accl[i][j] += a[i] * bl[j];
                accr[i][j] += a[i] * br[j];
            }
        }
    }
    #pragma unroll
    for (int i = 0; i < 4; ++i) {
        int m = bm + n0 + i;
        ushort4 pv;
        pv.x = f2bf(accl[i][0]); pv.y = f2bf(accl[i][1]);
        pv.z = f2bf(accl[i][2]); pv.w = f2bf(accl[i][3]);
        ((ushort4*)Pb)[(size_t)m * 16 + tx] = pv;
        ((float4*)Q)[(size_t)m * 16 + tx] =
            make_float4(accr[i][0], accr[i][1], accr[i][2], accr[i][3]);
    }
}

__global__ __launch_bounds__(256) void k_agg(
    const unsigned short* __restrict__ Pb, const float* __restrict__ Q,
    const float* __restrict__ bias,
    const int* __restrict__ offs, const int* __restrict__ sorted_src,
    float* __restrict__ out, int n, int relu) {
    const int wid  = (blockIdx.x * 256 + threadIdx.x) >> 6;
    const int lane = threadIdx.x & 63;
    if (wid >= n) return;
    const int s0 = offs[wid], s1 = offs[wid + 1];
    float acc = 0.f;
    int e = s0;
    for (; e + 7 < s1; e += 8) {
        int si[8];
        #pragma unroll
        for (int j = 0; j < 8; ++j) si[j] = sorted_src[e + j];
        float v[8];
        #pragma unroll
        for (int j = 0; j < 8; ++j) v[j] = bf2f(Pb[(size_t)si[j] * 64 + lane]);
        #pragma unroll
        for (int j = 0; j < 8; ++j) acc += v[j];
    }
    for (; e < s1; ++e) acc += bf2f(Pb[(size_t)sorted_src[e] * 64 + lane]);
    float cnt = (float)(s1 - s0);
    float v = acc * (1.0f / fmaxf(cnt, 1.0f)) + bias[lane] + Q[(size_t)wid * 64 + lane];
    if (relu) v = fmaxf(v, 0.f);
    out[(size_t)wid * 64 + lane] = v;
}

// ================================ launcher =================================

extern "C" void kernel_launch(void* const* d_in, const int* in_sizes, int n_in,
                              void* d_out, int out_size, void* d_ws, size_t ws_size,
                              hipStream_t stream) {
    const float* x   = (const float*)d_in[0];
    const int*  edge = (const int*)d_in[1];

    const int N = in_sizes[0] / 128;   // 40000
    const int E = in_sizes[1] / 2;     // 640000
    const int* src = edge;
    const int* dst = edge + E;

    char* w = (char*)d_ws;
    auto carve = [&](size_t bytes) {
        char* p = w; w += (bytes + 255) & ~(size_t)255; return p;
    };
    unsigned short* Pb = (unsigned short*)carve((size_t)N * 64 * 2);
    float* Q    = (float*)carve((size_t)N * 64 * 4);
    float* H    = (float*)carve((size_t)N * 64 * 4);
    float* WT1l = (float*)carve(128 * 64 * 4);
    float* WT1r = (float*)carve(128 * 64 * 4);
    float* WT2l = (float*)carve(64 * 64 * 4);
    float* WT2r = (float*)carve(64 * 64 * 4);
    int* deg      = (int*)carve((size_t)N * 4);
    int* cursor   = (int*)carve((size_t)N * 4);
    int* sorted   = (int*)carve((size_t)E * 4);
    int* offs     = (int*)carve((size_t)(N + 1) * 4);
    int* partials = (int*)carve(MAXGRID * 4);

    // capacity probe (host-only, deterministic, graph-capture-safe)
    int occ = 0, numCU = 0, dev = 0;
    hipError_t e1 = hipGetDevice(&dev);
    hipError_t e2 = hipDeviceGetAttribute(&numCU,
                        hipDeviceAttributeMultiprocessorCount, dev);
    hipError_t e3 = hipOccupancyMaxActiveBlocksPerMultiprocessor(
                        &occ, (const void*)k_mega, BLK, 0);
    int coopGrid = 0;
    if (e1 == hipSuccess && e2 == hipSuccess && e3 == hipSuccess && occ > 0)
        coopGrid = occ * numCU;
    if (coopGrid > MAXGRID) coopGrid = MAXGRID;

    if (coopGrid >= 128) {
        Args ha;
        ha.x = x; ha.src = src; ha.dst = dst;
        ha.W1l = (const float*)d_in[2]; ha.b1l = (const float*)d_in[3];
        ha.W1r = (const float*)d_in[4];
        ha.W2l = (const float*)d_in[5]; ha.b2l = (const float*)d_in[6];
        ha.W2r = (const float*)d_in[7];
        ha.z = (float*)d_out;
        ha.Pb = Pb; ha.Q = Q; ha.H = H;
        ha.WT1l = WT1l; ha.WT1r = WT1r; ha.WT2l = WT2l; ha.WT2r = WT2r;
        ha.deg = deg; ha.cursor = cursor; ha.sorted = sorted;
        ha.offs = offs; ha.partials = partials;
        ha.N = N; ha.E = E;
        void* kargs[] = { (void*)&ha };
        hipLaunchCooperativeKernel((const void*)k_mega, dim3(coopGrid), dim3(BLK),
                                   kargs, 0, stream);
    } else {
        const float* W1l = (const float*)d_in[2];
        const float* b1l = (const float*)d_in[3];
        const float* W1r = (const float*)d_in[4];
        const float* W2l = (const float*)d_in[5];
        const float* b2l = (const float*)d_in[6];
        const float* W2r = (const float*)d_in[7];
        float* zout = (float*)d_out;
        const int gE = (E + 255) / 256;
        const int gN = (N + 255) / 256;   // 157 <= 256
        k_transpose<<<32, 256, 0, stream>>>(W1l, W1r, W2l, W2r,
                                            WT1l, WT1r, WT2l, WT2r);
        hipMemsetAsync(deg, 0, (size_t)N * 4, stream);
        k_count<<<gE, 256, 0, stream>>>(dst, deg, E);
        k_scan_local<<<gN, 256, 0, stream>>>(deg, offs, partials, N);
        k_scan_partials<<<1, 256, 0, stream>>>(partials, offs + N, gN);
        k_scan_add<<<gN, 256, 0, stream>>>(partials, offs, cursor, N);
        k_scatter<<<gE, 256, 0, stream>>>(src, dst, cursor, sorted, E);
        k_gemm_dual<128><<<N / 64, 256, 0, stream>>>(x, WT1l, WT1r, Pb, Q);
        k_agg<<<(N * 64 + 255) / 256, 256, 0, stream>>>(Pb, Q, b1l, offs, sorted, H, N, 1);
        k_gemm_dual<64><<<N / 64, 256, 0, stream>>>(H, WT2l, WT2r, Pb, Q);
        k_agg<<<(N * 64 + 255) / 256, 256, 0, stream>>>(Pb, Q, b2l, offs, sorted, zout, N, 0);
    }
}

// Round 7
// 266.134 us; speedup vs baseline: 2.0690x; 2.0690x over previous
//
#include <hip/hip_runtime.h>

#define INDIM 128
#define HID 64

__device__ __forceinline__ float bf2f(unsigned short u) {
    union { unsigned int i; float f; } c; c.i = ((unsigned int)u) << 16; return c.f;
}
__device__ __forceinline__ unsigned short f2bf(float f) {
    union { float f; unsigned int i; } c; c.f = f;
    return (unsigned short)((c.i + 0x7FFFu + ((c.i >> 16) & 1u)) >> 16);
}

// ---------------- P0: zero deg + transpose weights -------------------------

__global__ __launch_bounds__(256) void k_prep(
    const float* __restrict__ W1l, const float* __restrict__ W1r,
    const float* __restrict__ W2l, const float* __restrict__ W2r,
    float* __restrict__ WT1l, float* __restrict__ WT1r,
    float* __restrict__ WT2l, float* __restrict__ WT2r,
    int* __restrict__ deg, int n) {
    int gtid = blockIdx.x * 256 + threadIdx.x;
    if (gtid < n) deg[gtid] = 0;
    if (gtid < 64 * 128) {
        int j = gtid >> 7, k = gtid & 127;
        WT1l[k * 64 + j] = W1l[gtid];
        WT1r[k * 64 + j] = W1r[gtid];
    }
    if (gtid < 64 * 64) {
        int j = gtid >> 6, k = gtid & 63;
        WT2l[k * 64 + j] = W2l[gtid];
        WT2r[k * 64 + j] = W2r[gtid];
    }
}

// ---------------- P1: gemm1 (x -> Pb,Q) + edge-count histogram -------------

__global__ __launch_bounds__(256) void k_gemm1_count(
    const float* __restrict__ A,        // x [N][128]
    const float* __restrict__ WTl, const float* __restrict__ WTr,
    unsigned short* __restrict__ Pb, float* __restrict__ Q,
    const int* __restrict__ dst, int* __restrict__ deg, int N, int E) {
    __shared__ float As[64][INDIM + 1];
    const int tid = threadIdx.x;
    const int bm  = blockIdx.x * 64;

    for (int idx = tid; idx < 64 * 32; idx += 256) {
        int row = idx >> 5, kq = idx & 31;
        const float4 v = ((const float4*)A)[(size_t)(bm + row) * 32 + kq];
        As[row][kq * 4 + 0] = v.x; As[row][kq * 4 + 1] = v.y;
        As[row][kq * 4 + 2] = v.z; As[row][kq * 4 + 3] = v.w;
    }
    __syncthreads();

    const int tx = tid & 15, ty = tid >> 4;
    const int n0 = ty * 4;
    float accl[4][4] = {}, accr[4][4] = {};
    #pragma unroll 8
    for (int k = 0; k < INDIM; ++k) {
        float a[4];
        #pragma unroll
        for (int i = 0; i < 4; ++i) a[i] = As[n0 + i][k];
        const float4 blv = ((const float4*)WTl)[k * 16 + tx];
        const float4 brv = ((const float4*)WTr)[k * 16 + tx];
        const float bl[4] = {blv.x, blv.y, blv.z, blv.w};
        const float br[4] = {brv.x, brv.y, brv.z, brv.w};
        #pragma unroll
        for (int i = 0; i < 4; ++i) {
            #pragma unroll
            for (int j = 0; j < 4; ++j) {
                accl[i][j] += a[i] * bl[j];
                accr[i][j] += a[i] * br[j];
            }
        }
    }
    #pragma unroll
    for (int i = 0; i < 4; ++i) {
        int m = bm + n0 + i;
        ushort4 pv;
        pv.x = f2bf(accl[i][0]); pv.y = f2bf(accl[i][1]);
        pv.z = f2bf(accl[i][2]); pv.w = f2bf(accl[i][3]);
        ((ushort4*)Pb)[(size_t)m * 16 + tx] = pv;
        ((float4*)Q)[(size_t)m * 16 + tx] =
            make_float4(accr[i][0], accr[i][1], accr[i][2], accr[i][3]);
    }

    // fused histogram (independent output; latency hides under GEMM VALU)
    const int stride = gridDim.x * 256;
    for (int e = blockIdx.x * 256 + tid; e < E; e += stride)
        atomicAdd(&deg[dst[e]], 1);
}

// ---------------- P2a/b/c: hierarchical exclusive scan ---------------------

__global__ __launch_bounds__(256) void k_scan_local(const int* __restrict__ deg,
                                                    int* __restrict__ offs,
                                                    int* __restrict__ partials, int n) {
    __shared__ int wsum[4];
    const int tid = threadIdx.x;
    const int i = blockIdx.x * 256 + tid;
    const int lane = tid & 63, w = tid >> 6;
    int v = (i < n) ? deg[i] : 0;
    int s = v;
    #pragma unroll
    for (int off = 1; off < 64; off <<= 1) {
        int t = __shfl_up(s, off, 64);
        if (lane >= off) s += t;
    }
    if (lane == 63) wsum[w] = s;
    __syncthreads();
    int wbase = 0;
    #pragma unroll
    for (int ww = 0; ww < 3; ++ww) wbase += (ww < w) ? wsum[ww] : 0;
    if (i < n) offs[i] = wbase + s - v;
    if (tid == 255) partials[blockIdx.x] = wbase + s;
}

__global__ __launch_bounds__(256) void k_scan_partials(int* __restrict__ partials,
                                                       int* __restrict__ total, int B) {
    __shared__ int wsum[4];
    const int tid = threadIdx.x;
    const int lane = tid & 63, w = tid >> 6;
    int v = (tid < B) ? partials[tid] : 0;
    int s = v;
    #pragma unroll
    for (int off = 1; off < 64; off <<= 1) {
        int t = __shfl_up(s, off, 64);
        if (lane >= off) s += t;
    }
    if (lane == 63) wsum[w] = s;
    __syncthreads();
    int wbase = 0;
    #pragma unroll
    for (int ww = 0; ww < 3; ++ww) wbase += (ww < w) ? wsum[ww] : 0;
    if (tid < B) partials[tid] = wbase + s - v;
    if (tid == 255) *total = wbase + s;
}

__global__ __launch_bounds__(256) void k_scan_add(const int* __restrict__ partials,
                                                  int* __restrict__ offs,
                                                  int* __restrict__ cursor, int n) {
    int i = blockIdx.x * 256 + threadIdx.x;
    if (i < n) {
        int o = offs[i] + partials[blockIdx.x];
        offs[i] = o;
        cursor[i] = o;
    }
}

// ---------------- P3: scatter edges into CSR order -------------------------

__global__ __launch_bounds__(256) void k_scatter(const int* __restrict__ src,
                                                 const int* __restrict__ dst,
                                                 int* __restrict__ cursor,
                                                 int* __restrict__ sorted_src, int E) {
    int e = blockIdx.x * 256 + threadIdx.x;
    if (e < E) {
        int p = atomicAdd(&cursor[dst[e]], 1);
        sorted_src[p] = src[e];
    }
}

// ---------------- P4: fused agg1 (+ReLU) -> LDS -> gemm2 -------------------
// Block t owns nodes [64t, 64t+64). Wave w aggregates nodes [16w,16w+16)
// (lane = feature) into Hs, then the block GEMMs Hs against WT2 from LDS.

__global__ __launch_bounds__(256) void k_agg1_gemm2(
    const unsigned short* __restrict__ Pb, const float* __restrict__ Q,
    const float* __restrict__ b1,
    const int* __restrict__ offs, const int* __restrict__ sorted,
    const float* __restrict__ WTl, const float* __restrict__ WTr,
    unsigned short* __restrict__ Pb2, float* __restrict__ Q2, int N) {
    __shared__ float Hs[64][HID + 1];
    const int tid = threadIdx.x;
    const int bm = blockIdx.x * 64;
    const int lane = tid & 63, w = tid >> 6;
    const float bv = b1[lane];

    for (int r = 0; r < 16; ++r) {
        const int node = bm + w * 16 + r;
        if (node >= N) break;
        const int s0 = offs[node], s1 = offs[node + 1];
        float acc = 0.f;
        int e = s0;
        for (; e + 7 < s1; e += 8) {
            int si[8];
            #pragma unroll
            for (int j = 0; j < 8; ++j) si[j] = sorted[e + j];
            float vv[8];
            #pragma unroll
            for (int j = 0; j < 8; ++j) vv[j] = bf2f(Pb[(size_t)si[j] * 64 + lane]);
            #pragma unroll
            for (int j = 0; j < 8; ++j) acc += vv[j];
        }
        for (; e < s1; ++e) acc += bf2f(Pb[(size_t)sorted[e] * 64 + lane]);
        float cnt = (float)(s1 - s0);
        float hv = acc * (1.0f / fmaxf(cnt, 1.0f)) + bv + Q[(size_t)node * 64 + lane];
        Hs[w * 16 + r][lane] = fmaxf(hv, 0.f);     // ReLU
    }
    __syncthreads();

    const int tx = tid & 15, ty = tid >> 4;
    const int n0 = ty * 4;
    float accl[4][4] = {}, accr[4][4] = {};
    #pragma unroll 8
    for (int k = 0; k < HID; ++k) {
        float a[4];
        #pragma unroll
        for (int i = 0; i < 4; ++i) a[i] = Hs[n0 + i][k];
        const float4 blv = ((const float4*)WTl)[k * 16 + tx];
        const float4 brv = ((const float4*)WTr)[k * 16 + tx];
        const float bl[4] = {blv.x, blv.y, blv.z, blv.w};
        const float br[4] = {brv.x, brv.y, brv.z, brv.w};
        #pragma unroll
        for (int i = 0; i < 4; ++i) {
            #pragma unroll
            for (int j = 0; j < 4; ++j) {
                accl[i][j] += a[i] * bl[j];
                accr[i][j] += a[i] * br[j];
            }
        }
    }
    #pragma unroll
    for (int i = 0; i < 4; ++i) {
        int m = bm + n0 + i;
        if (m < N) {
            ushort4 pv;
            pv.x = f2bf(accl[i][0]); pv.y = f2bf(accl[i][1]);
            pv.z = f2bf(accl[i][2]); pv.w = f2bf(accl[i][3]);
            ((ushort4*)Pb2)[(size_t)m * 16 + tx] = pv;
            ((float4*)Q2)[(size_t)m * 16 + tx] =
                make_float4(accr[i][0], accr[i][1], accr[i][2], accr[i][3]);
        }
    }
}

// ---------------- P5: agg2 -> z --------------------------------------------

__global__ __launch_bounds__(256) void k_agg2(
    const unsigned short* __restrict__ Pb2, const float* __restrict__ Q2,
    const float* __restrict__ b2,
    const int* __restrict__ offs, const int* __restrict__ sorted,
    float* __restrict__ z, int N) {
    const int wid  = (blockIdx.x * 256 + threadIdx.x) >> 6;
    const int lane = threadIdx.x & 63;
    if (wid >= N) return;
    const int s0 = offs[wid], s1 = offs[wid + 1];
    float acc = 0.f;
    int e = s0;
    for (; e + 7 < s1; e += 8) {
        int si[8];
        #pragma unroll
        for (int j = 0; j < 8; ++j) si[j] = sorted[e + j];
        float vv[8];
        #pragma unroll
        for (int j = 0; j < 8; ++j) vv[j] = bf2f(Pb2[(size_t)si[j] * 64 + lane]);
        #pragma unroll
        for (int j = 0; j < 8; ++j) acc += vv[j];
    }
    for (; e < s1; ++e) acc += bf2f(Pb2[(size_t)sorted[e] * 64 + lane]);
    float cnt = (float)(s1 - s0);
    z[(size_t)wid * 64 + lane] =
        acc * (1.0f / fmaxf(cnt, 1.0f)) + b2[lane] + Q2[(size_t)wid * 64 + lane];
}

// ================================ launcher =================================

extern "C" void kernel_launch(void* const* d_in, const int* in_sizes, int n_in,
                              void* d_out, int out_size, void* d_ws, size_t ws_size,
                              hipStream_t stream) {
    const float* x   = (const float*)d_in[0];
    const int*  edge = (const int*)d_in[1];
    const float* W1l = (const float*)d_in[2];
    const float* b1l = (const float*)d_in[3];
    const float* W1r = (const float*)d_in[4];
    const float* W2l = (const float*)d_in[5];
    const float* b2l = (const float*)d_in[6];
    const float* W2r = (const float*)d_in[7];

    const int N = in_sizes[0] / INDIM;   // 40000
    const int E = in_sizes[1] / 2;       // 640000
    const int* src = edge;
    const int* dst = edge + E;

    char* w = (char*)d_ws;
    auto carve = [&](size_t bytes) {
        char* p = w; w += (bytes + 255) & ~(size_t)255; return p;
    };
    unsigned short* Pb  = (unsigned short*)carve((size_t)N * 64 * 2);
    unsigned short* Pb2 = (unsigned short*)carve((size_t)N * 64 * 2);
    float* Q    = (float*)carve((size_t)N * 64 * 4);
    float* Q2   = (float*)carve((size_t)N * 64 * 4);
    float* WT1l = (float*)carve(128 * 64 * 4);
    float* WT1r = (float*)carve(128 * 64 * 4);
    float* WT2l = (float*)carve(64 * 64 * 4);
    float* WT2r = (float*)carve(64 * 64 * 4);
    int* deg      = (int*)carve((size_t)N * 4);
    int* cursor   = (int*)carve((size_t)N * 4);
    int* sorted   = (int*)carve((size_t)E * 4);
    int* offs     = (int*)carve((size_t)(N + 1) * 4);
    int* partials = (int*)carve(256 * 4);

    float* zout = (float*)d_out;

    const int gE = (E + 255) / 256;      // 2500
    const int gT = (N + 63) / 64;        // 625 gemm tiles
    const int gN = (N + 255) / 256;      // 157 (<= 256)

    k_prep<<<gN, 256, 0, stream>>>(W1l, W1r, W2l, W2r,
                                   WT1l, WT1r, WT2l, WT2r, deg, N);
    k_gemm1_count<<<gT, 256, 0, stream>>>(x, WT1l, WT1r, Pb, Q, dst, deg, N, E);
    k_scan_local<<<gN, 256, 0, stream>>>(deg, offs, partials, N);
    k_scan_partials<<<1, 256, 0, stream>>>(partials, offs + N, gN);
    k_scan_add<<<gN, 256, 0, stream>>>(partials, offs, cursor, N);
    k_scatter<<<gE, 256, 0, stream>>>(src, dst, cursor, sorted, E);
    k_agg1_gemm2<<<gT, 256, 0, stream>>>(Pb, Q, b1l, offs, sorted,
                                         WT2l, WT2r, Pb2, Q2, N);
    k_agg2<<<(N * 64 + 255) / 256, 256, 0, stream>>>(Pb2, Q2, b2l, offs, sorted,
                                                     zout, N);
}

// Round 8
// 253.296 us; speedup vs baseline: 2.1739x; 1.0507x over previous
//
#include <hip/hip_runtime.h>

#define INDIM 128
#define HID 64

__device__ __forceinline__ float bf2f(unsigned short u) {
    union { unsigned int i; float f; } c; c.i = ((unsigned int)u) << 16; return c.f;
}
__device__ __forceinline__ unsigned short f2bf(float f) {
    union { float f; unsigned int i; } c; c.f = f;
    return (unsigned short)((c.i + 0x7FFFu + ((c.i >> 16) & 1u)) >> 16);
}

// ---------------- P0: zero deg + transpose weights -------------------------

__global__ __launch_bounds__(256) void k_prep(
    const float* __restrict__ W1l, const float* __restrict__ W1r,
    const float* __restrict__ W2l, const float* __restrict__ W2r,
    float* __restrict__ WT1l, float* __restrict__ WT1r,
    float* __restrict__ WT2l, float* __restrict__ WT2r,
    int* __restrict__ deg, int n) {
    int gtid = blockIdx.x * 256 + threadIdx.x;
    if (gtid < n) deg[gtid] = 0;
    if (gtid < 64 * 128) {
        int j = gtid >> 7, k = gtid & 127;
        WT1l[k * 64 + j] = W1l[gtid];
        WT1r[k * 64 + j] = W1r[gtid];
    }
    if (gtid < 64 * 64) {
        int j = gtid >> 6, k = gtid & 63;
        WT2l[k * 64 + j] = W2l[gtid];
        WT2r[k * 64 + j] = W2r[gtid];
    }
}

// ---------------- P1: gemm1 (x -> Pb,Q) + edge-count histogram -------------

__global__ __launch_bounds__(256) void k_gemm1_count(
    const float* __restrict__ A,        // x [N][128]
    const float* __restrict__ WTl, const float* __restrict__ WTr,
    unsigned short* __restrict__ Pb, float* __restrict__ Q,
    const int* __restrict__ dst, int* __restrict__ deg, int N, int E) {
    __shared__ float As[64][INDIM + 1];
    const int tid = threadIdx.x;
    const int bm  = blockIdx.x * 64;

    for (int idx = tid; idx < 64 * 32; idx += 256) {
        int row = idx >> 5, kq = idx & 31;
        const float4 v = ((const float4*)A)[(size_t)(bm + row) * 32 + kq];
        As[row][kq * 4 + 0] = v.x; As[row][kq * 4 + 1] = v.y;
        As[row][kq * 4 + 2] = v.z; As[row][kq * 4 + 3] = v.w;
    }
    __syncthreads();

    const int tx = tid & 15, ty = tid >> 4;
    const int n0 = ty * 4;
    float accl[4][4] = {}, accr[4][4] = {};
    #pragma unroll 8
    for (int k = 0; k < INDIM; ++k) {
        float a[4];
        #pragma unroll
        for (int i = 0; i < 4; ++i) a[i] = As[n0 + i][k];
        const float4 blv = ((const float4*)WTl)[k * 16 + tx];
        const float4 brv = ((const float4*)WTr)[k * 16 + tx];
        const float bl[4] = {blv.x, blv.y, blv.z, blv.w};
        const float br[4] = {brv.x, brv.y, brv.z, brv.w};
        #pragma unroll
        for (int i = 0; i < 4; ++i) {
            #pragma unroll
            for (int j = 0; j < 4; ++j) {
                accl[i][j] += a[i] * bl[j];
                accr[i][j] += a[i] * br[j];
            }
        }
    }
    #pragma unroll
    for (int i = 0; i < 4; ++i) {
        int m = bm + n0 + i;
        ushort4 pv;
        pv.x = f2bf(accl[i][0]); pv.y = f2bf(accl[i][1]);
        pv.z = f2bf(accl[i][2]); pv.w = f2bf(accl[i][3]);
        ((ushort4*)Pb)[(size_t)m * 16 + tx] = pv;
        ((float4*)Q)[(size_t)m * 16 + tx] =
            make_float4(accr[i][0], accr[i][1], accr[i][2], accr[i][3]);
    }

    // fused histogram (independent output; latency hides under GEMM VALU)
    const int stride = gridDim.x * 256;
    for (int e = blockIdx.x * 256 + tid; e < E; e += stride)
        atomicAdd(&deg[dst[e]], 1);
}

// ---------------- P2a/b/c: hierarchical exclusive scan ---------------------

__global__ __launch_bounds__(256) void k_scan_local(const int* __restrict__ deg,
                                                    int* __restrict__ offs,
                                                    int* __restrict__ partials, int n) {
    __shared__ int wsum[4];
    const int tid = threadIdx.x;
    const int i = blockIdx.x * 256 + tid;
    const int lane = tid & 63, w = tid >> 6;
    int v = (i < n) ? deg[i] : 0;
    int s = v;
    #pragma unroll
    for (int off = 1; off < 64; off <<= 1) {
        int t = __shfl_up(s, off, 64);
        if (lane >= off) s += t;
    }
    if (lane == 63) wsum[w] = s;
    __syncthreads();
    int wbase = 0;
    #pragma unroll
    for (int ww = 0; ww < 3; ++ww) wbase += (ww < w) ? wsum[ww] : 0;
    if (i < n) offs[i] = wbase + s - v;
    if (tid == 255) partials[blockIdx.x] = wbase + s;
}

__global__ __launch_bounds__(256) void k_scan_partials(int* __restrict__ partials,
                                                       int* __restrict__ total, int B) {
    __shared__ int wsum[4];
    const int tid = threadIdx.x;
    const int lane = tid & 63, w = tid >> 6;
    int v = (tid < B) ? partials[tid] : 0;
    int s = v;
    #pragma unroll
    for (int off = 1; off < 64; off <<= 1) {
        int t = __shfl_up(s, off, 64);
        if (lane >= off) s += t;
    }
    if (lane == 63) wsum[w] = s;
    __syncthreads();
    int wbase = 0;
    #pragma unroll
    for (int ww = 0; ww < 3; ++ww) wbase += (ww < w) ? wsum[ww] : 0;
    if (tid < B) partials[tid] = wbase + s - v;
    if (tid == 255) *total = wbase + s;
}

__global__ __launch_bounds__(256) void k_scan_add(const int* __restrict__ partials,
                                                  int* __restrict__ offs,
                                                  int* __restrict__ cursor, int n) {
    int i = blockIdx.x * 256 + threadIdx.x;
    if (i < n) {
        int o = offs[i] + partials[blockIdx.x];
        offs[i] = o;
        cursor[i] = o;
    }
}

// ---------------- P3: scatter edges into CSR order -------------------------

__global__ __launch_bounds__(256) void k_scatter(const int* __restrict__ src,
                                                 const int* __restrict__ dst,
                                                 int* __restrict__ cursor,
                                                 int* __restrict__ sorted_src, int E) {
    int e = blockIdx.x * 256 + threadIdx.x;
    if (e < E) {
        int p = atomicAdd(&cursor[dst[e]], 1);
        sorted_src[p] = src[e];
    }
}

// ---------------- P4: fused agg1 (+ReLU) -> LDS -> gemm2 -------------------
// 512 threads = 8 waves; wave w aggregates nodes [8w, 8w+8) of the block's
// 64-node tile (lane = feature) into Hs, then the block GEMMs Hs vs WT2.
// 512 threads doubles waves-in-flight vs 256 (occupancy 30% cap -> 61%).

__global__ __launch_bounds__(512) void k_agg1_gemm2(
    const unsigned short* __restrict__ Pb, const float* __restrict__ Q,
    const float* __restrict__ b1,
    const int* __restrict__ offs, const int* __restrict__ sorted,
    const float* __restrict__ WTl, const float* __restrict__ WTr,
    unsigned short* __restrict__ Pb2, float* __restrict__ Q2, int N) {
    __shared__ float Hs[64][HID + 1];
    const int tid = threadIdx.x;
    const int bm = blockIdx.x * 64;
    const int lane = tid & 63, w = tid >> 6;
    const float bv = b1[lane];

    #pragma unroll
    for (int r = 0; r < 8; ++r) {
        const int node = bm + w * 8 + r;
        if (node >= N) break;
        const int s0 = offs[node], s1 = offs[node + 1];
        float acc = 0.f;
        int e = s0;
        for (; e + 7 < s1; e += 8) {
            int si[8];
            #pragma unroll
            for (int j = 0; j < 8; ++j) si[j] = sorted[e + j];
            float vv[8];
            #pragma unroll
            for (int j = 0; j < 8; ++j) vv[j] = bf2f(Pb[(size_t)si[j] * 64 + lane]);
            #pragma unroll
            for (int j = 0; j < 8; ++j) acc += vv[j];
        }
        for (; e < s1; ++e) acc += bf2f(Pb[(size_t)sorted[e] * 64 + lane]);
        float cnt = (float)(s1 - s0);
        float hv = acc * (1.0f / fmaxf(cnt, 1.0f)) + bv + Q[(size_t)node * 64 + lane];
        Hs[w * 8 + r][lane] = fmaxf(hv, 0.f);     // ReLU
    }
    __syncthreads();

    // gemm2: 64x64 tile, 512 threads -> 2 rows x 4 cols x 2 mats per thread
    const int tx = tid & 15, ty = tid >> 4;     // ty in [0,32)
    const int n0 = ty * 2;
    float accl[2][4] = {}, accr[2][4] = {};
    #pragma unroll 8
    for (int k = 0; k < HID; ++k) {
        float a[2];
        #pragma unroll
        for (int i = 0; i < 2; ++i) a[i] = Hs[n0 + i][k];
        const float4 blv = ((const float4*)WTl)[k * 16 + tx];
        const float4 brv = ((const float4*)WTr)[k * 16 + tx];
        const float bl[4] = {blv.x, blv.y, blv.z, blv.w};
        const float br[4] = {brv.x, brv.y, brv.z, brv.w};
        #pragma unroll
        for (int i = 0; i < 2; ++i) {
            #pragma unroll
            for (int j = 0; j < 4; ++j) {
                accl[i][j] += a[i] * bl[j];
                accr[i][j] += a[i] * br[j];
            }
        }
    }
    #pragma unroll
    for (int i = 0; i < 2; ++i) {
        int m = bm + n0 + i;
        if (m < N) {
            ushort4 pv;
            pv.x = f2bf(accl[i][0]); pv.y = f2bf(accl[i][1]);
            pv.z = f2bf(accl[i][2]); pv.w = f2bf(accl[i][3]);
            ((ushort4*)Pb2)[(size_t)m * 16 + tx] = pv;
            ((float4*)Q2)[(size_t)m * 16 + tx] =
                make_float4(accr[i][0], accr[i][1], accr[i][2], accr[i][3]);
        }
    }
}

// ---------------- P5: agg2 -> z --------------------------------------------

__global__ __launch_bounds__(256) void k_agg2(
    const unsigned short* __restrict__ Pb2, const float* __restrict__ Q2,
    const float* __restrict__ b2,
    const int* __restrict__ offs, const int* __restrict__ sorted,
    float* __restrict__ z, int N) {
    const int wid  = (blockIdx.x * 256 + threadIdx.x) >> 6;
    const int lane = threadIdx.x & 63;
    if (wid >= N) return;
    const int s0 = offs[wid], s1 = offs[wid + 1];
    float acc = 0.f;
    int e = s0;
    for (; e + 7 < s1; e += 8) {
        int si[8];
        #pragma unroll
        for (int j = 0; j < 8; ++j) si[j] = sorted[e + j];
        float vv[8];
        #pragma unroll
        for (int j = 0; j < 8; ++j) vv[j] = bf2f(Pb2[(size_t)si[j] * 64 + lane]);
        #pragma unroll
        for (int j = 0; j < 8; ++j) acc += vv[j];
    }
    for (; e < s1; ++e) acc += bf2f(Pb2[(size_t)sorted[e] * 64 + lane]);
    float cnt = (float)(s1 - s0);
    z[(size_t)wid * 64 + lane] =
        acc * (1.0f / fmaxf(cnt, 1.0f)) + b2[lane] + Q2[(size_t)wid * 64 + lane];
}

// ================================ launcher =================================

extern "C" void kernel_launch(void* const* d_in, const int* in_sizes, int n_in,
                              void* d_out, int out_size, void* d_ws, size_t ws_size,
                              hipStream_t stream) {
    const float* x   = (const float*)d_in[0];
    const int*  edge = (const int*)d_in[1];
    const float* W1l = (const float*)d_in[2];
    const float* b1l = (const float*)d_in[3];
    const float* W1r = (const float*)d_in[4];
    const float* W2l = (const float*)d_in[5];
    const float* b2l = (const float*)d_in[6];
    const float* W2r = (const float*)d_in[7];

    const int N = in_sizes[0] / INDIM;   // 40000
    const int E = in_sizes[1] / 2;       // 640000
    const int* src = edge;
    const int* dst = edge + E;

    char* w = (char*)d_ws;
    auto carve = [&](size_t bytes) {
        char* p = w; w += (bytes + 255) & ~(size_t)255; return p;
    };
    unsigned short* Pb  = (unsigned short*)carve((size_t)N * 64 * 2);
    unsigned short* Pb2 = (unsigned short*)carve((size_t)N * 64 * 2);
    float* Q    = (float*)carve((size_t)N * 64 * 4);
    float* Q2   = (float*)carve((size_t)N * 64 * 4);
    float* WT1l = (float*)carve(128 * 64 * 4);
    float* WT1r = (float*)carve(128 * 64 * 4);
    float* WT2l = (float*)carve(64 * 64 * 4);
    float* WT2r = (float*)carve(64 * 64 * 4);
    int* deg      = (int*)carve((size_t)N * 4);
    int* cursor   = (int*)carve((size_t)N * 4);
    int* sorted   = (int*)carve((size_t)E * 4);
    int* offs     = (int*)carve((size_t)(N + 1) * 4);
    int* partials = (int*)carve(256 * 4);

    float* zout = (float*)d_out;

    const int gE = (E + 255) / 256;      // 2500
    const int gT = (N + 63) / 64;        // 625 tiles
    const int gN = (N + 255) / 256;      // 157 (<= 256)

    k_prep<<<gN, 256, 0, stream>>>(W1l, W1r, W2l, W2r,
                                   WT1l, WT1r, WT2l, WT2r, deg, N);
    k_gemm1_count<<<gT, 256, 0, stream>>>(x, WT1l, WT1r, Pb, Q, dst, deg, N, E);
    k_scan_local<<<gN, 256, 0, stream>>>(deg, offs, partials, N);
    k_scan_partials<<<1, 256, 0, stream>>>(partials, offs + N, gN);
    k_scan_add<<<gN, 256, 0, stream>>>(partials, offs, cursor, N);
    k_scatter<<<gE, 256, 0, stream>>>(src, dst, cursor, sorted, E);
    k_agg1_gemm2<<<gT, 512, 0, stream>>>(Pb, Q, b1l, offs, sorted,
                                         WT2l, WT2r, Pb2, Q2, N);
    k_agg2<<<(N * 64 + 255) / 256, 256, 0, stream>>>(Pb2, Q2, b2l, offs, sorted,
                                                     zout, N);
}

// Round 9
// 236.665 us; speedup vs baseline: 2.3266x; 1.0703x over previous
//
#include <hip/hip_runtime.h>

#define INDIM 128
#define HID 64

__device__ __forceinline__ float bf2f(unsigned short u) {
    union { unsigned int i; float f; } c; c.i = ((unsigned int)u) << 16; return c.f;
}
__device__ __forceinline__ unsigned short f2bf(float f) {
    union { float f; unsigned int i; } c; c.f = f;
    return (unsigned short)((c.i + 0x7FFFu + ((c.i >> 16) & 1u)) >> 16);
}

// load 4 bf16 features (8B) from row `row`, feature group f4 -> 4 floats
__device__ __forceinline__ float4 gather4(const unsigned short* __restrict__ Pb,
                                          int row, int f4) {
    const uint2 v = *(const uint2*)&Pb[(size_t)row * 64 + f4 * 4];
    float4 r;
    r.x = bf2f((unsigned short)(v.x & 0xffffu));
    r.y = bf2f((unsigned short)(v.x >> 16));
    r.z = bf2f((unsigned short)(v.y & 0xffffu));
    r.w = bf2f((unsigned short)(v.y >> 16));
    return r;
}

// Aggregate one node's neighbor rows. Lane split: q = lane>>4 (edge quarter),
// f4 = lane&15 (4-feature group). One vmem instruction covers 4 edges
// (4 quarters x 16 lanes x 8B = 4 rows of 128B). After the cross-quarter
// shfl reduction ALL lanes hold the full sum for their f4 group.
__device__ __forceinline__ float4 agg_node(const unsigned short* __restrict__ Pb,
                                           const int* __restrict__ sorted,
                                           int s0, int s1, int q, int f4) {
    float4 acc = make_float4(0.f, 0.f, 0.f, 0.f);
    int e = s0;
    for (; e + 7 < s1; e += 8) {            // 8 edges per iter, 2 loads in flight
        const int sa = sorted[e + q];
        const int sb = sorted[e + 4 + q];
        const float4 va = gather4(Pb, sa, f4);
        const float4 vb = gather4(Pb, sb, f4);
        acc.x += va.x + vb.x; acc.y += va.y + vb.y;
        acc.z += va.z + vb.z; acc.w += va.w + vb.w;
    }
    for (; e < s1; e += 4) {                // masked tail, 4 edges per iter
        const int t = e + q;
        const int idx = (t < s1) ? t : (s1 - 1);
        const float m = (t < s1) ? 1.f : 0.f;
        const float4 v = gather4(Pb, sorted[idx], f4);
        acc.x += v.x * m; acc.y += v.y * m;
        acc.z += v.z * m; acc.w += v.w * m;
    }
    // combine the 4 quarters
    acc.x += __shfl_xor(acc.x, 16, 64); acc.y += __shfl_xor(acc.y, 16, 64);
    acc.z += __shfl_xor(acc.z, 16, 64); acc.w += __shfl_xor(acc.w, 16, 64);
    acc.x += __shfl_xor(acc.x, 32, 64); acc.y += __shfl_xor(acc.y, 32, 64);
    acc.z += __shfl_xor(acc.z, 32, 64); acc.w += __shfl_xor(acc.w, 32, 64);
    return acc;
}

// ---------------- P0: zero deg + transpose weights -------------------------

__global__ __launch_bounds__(256) void k_prep(
    const float* __restrict__ W1l, const float* __restrict__ W1r,
    const float* __restrict__ W2l, const float* __restrict__ W2r,
    float* __restrict__ WT1l, float* __restrict__ WT1r,
    float* __restrict__ WT2l, float* __restrict__ WT2r,
    int* __restrict__ deg, int n) {
    int gtid = blockIdx.x * 256 + threadIdx.x;
    if (gtid < n) deg[gtid] = 0;
    if (gtid < 64 * 128) {
        int j = gtid >> 7, k = gtid & 127;
        WT1l[k * 64 + j] = W1l[gtid];
        WT1r[k * 64 + j] = W1r[gtid];
    }
    if (gtid < 64 * 64) {
        int j = gtid >> 6, k = gtid & 63;
        WT2l[k * 64 + j] = W2l[gtid];
        WT2r[k * 64 + j] = W2r[gtid];
    }
}

// ---------------- P1: gemm1 (x -> Pb,Q) + edge-count histogram -------------

__global__ __launch_bounds__(256) void k_gemm1_count(
    const float* __restrict__ A,        // x [N][128]
    const float* __restrict__ WTl, const float* __restrict__ WTr,
    unsigned short* __restrict__ Pb, float* __restrict__ Q,
    const int* __restrict__ dst, int* __restrict__ deg, int N, int E) {
    __shared__ float As[64][INDIM + 1];
    const int tid = threadIdx.x;
    const int bm  = blockIdx.x * 64;

    for (int idx = tid; idx < 64 * 32; idx += 256) {
        int row = idx >> 5, kq = idx & 31;
        const float4 v = ((const float4*)A)[(size_t)(bm + row) * 32 + kq];
        As[row][kq * 4 + 0] = v.x; As[row][kq * 4 + 1] = v.y;
        As[row][kq * 4 + 2] = v.z; As[row][kq * 4 + 3] = v.w;
    }
    __syncthreads();

    const int tx = tid & 15, ty = tid >> 4;
    const int n0 = ty * 4;
    float accl[4][4] = {}, accr[4][4] = {};
    #pragma unroll 8
    for (int k = 0; k < INDIM; ++k) {
        float a[4];
        #pragma unroll
        for (int i = 0; i < 4; ++i) a[i] = As[n0 + i][k];
        const float4 blv = ((const float4*)WTl)[k * 16 + tx];
        const float4 brv = ((const float4*)WTr)[k * 16 + tx];
        const float bl[4] = {blv.x, blv.y, blv.z, blv.w};
        const float br[4] = {brv.x, brv.y, brv.z, brv.w};
        #pragma unroll
        for (int i = 0; i < 4; ++i) {
            #pragma unroll
            for (int j = 0; j < 4; ++j) {
                accl[i][j] += a[i] * bl[j];
                accr[i][j] += a[i] * br[j];
            }
        }
    }
    #pragma unroll
    for (int i = 0; i < 4; ++i) {
        int m = bm + n0 + i;
        ushort4 pv;
        pv.x = f2bf(accl[i][0]); pv.y = f2bf(accl[i][1]);
        pv.z = f2bf(accl[i][2]); pv.w = f2bf(accl[i][3]);
        ((ushort4*)Pb)[(size_t)m * 16 + tx] = pv;
        ((float4*)Q)[(size_t)m * 16 + tx] =
            make_float4(accr[i][0], accr[i][1], accr[i][2], accr[i][3]);
    }

    const int stride = gridDim.x * 256;
    for (int e = blockIdx.x * 256 + tid; e < E; e += stride)
        atomicAdd(&deg[dst[e]], 1);
}

// ---------------- P2a/b/c: hierarchical exclusive scan ---------------------

__global__ __launch_bounds__(256) void k_scan_local(const int* __restrict__ deg,
                                                    int* __restrict__ offs,
                                                    int* __restrict__ partials, int n) {
    __shared__ int wsum[4];
    const int tid = threadIdx.x;
    const int i = blockIdx.x * 256 + tid;
    const int lane = tid & 63, w = tid >> 6;
    int v = (i < n) ? deg[i] : 0;
    int s = v;
    #pragma unroll
    for (int off = 1; off < 64; off <<= 1) {
        int t = __shfl_up(s, off, 64);
        if (lane >= off) s += t;
    }
    if (lane == 63) wsum[w] = s;
    __syncthreads();
    int wbase = 0;
    #pragma unroll
    for (int ww = 0; ww < 3; ++ww) wbase += (ww < w) ? wsum[ww] : 0;
    if (i < n) offs[i] = wbase + s - v;
    if (tid == 255) partials[blockIdx.x] = wbase + s;
}

__global__ __launch_bounds__(256) void k_scan_partials(int* __restrict__ partials,
                                                       int* __restrict__ total, int B) {
    __shared__ int wsum[4];
    const int tid = threadIdx.x;
    const int lane = tid & 63, w = tid >> 6;
    int v = (tid < B) ? partials[tid] : 0;
    int s = v;
    #pragma unroll
    for (int off = 1; off < 64; off <<= 1) {
        int t = __shfl_up(s, off, 64);
        if (lane >= off) s += t;
    }
    if (lane == 63) wsum[w] = s;
    __syncthreads();
    int wbase = 0;
    #pragma unroll
    for (int ww = 0; ww < 3; ++ww) wbase += (ww < w) ? wsum[ww] : 0;
    if (tid < B) partials[tid] = wbase + s - v;
    if (tid == 255) *total = wbase + s;
}

__global__ __launch_bounds__(256) void k_scan_add(const int* __restrict__ partials,
                                                  int* __restrict__ offs,
                                                  int* __restrict__ cursor, int n) {
    int i = blockIdx.x * 256 + threadIdx.x;
    if (i < n) {
        int o = offs[i] + partials[blockIdx.x];
        offs[i] = o;
        cursor[i] = o;
    }
}

// ---------------- P3: scatter edges into CSR order -------------------------

__global__ __launch_bounds__(256) void k_scatter(const int* __restrict__ src,
                                                 const int* __restrict__ dst,
                                                 int* __restrict__ cursor,
                                                 int* __restrict__ sorted_src, int E) {
    int e = blockIdx.x * 256 + threadIdx.x;
    if (e < E) {
        int p = atomicAdd(&cursor[dst[e]], 1);
        sorted_src[p] = src[e];
    }
}

// ---------------- P4: fused agg1 (+ReLU) -> LDS -> gemm2 -------------------
// 512 threads = 8 waves; wave w aggregates nodes [8w, 8w+8) via the 4-edge
// packed gather, writes Hs rows; then the block GEMMs Hs vs WT2.

__global__ __launch_bounds__(512) void k_agg1_gemm2(
    const unsigned short* __restrict__ Pb, const float* __restrict__ Q,
    const float* __restrict__ b1,
    const int* __restrict__ offs, const int* __restrict__ sorted,
    const float* __restrict__ WTl, const float* __restrict__ WTr,
    unsigned short* __restrict__ Pb2, float* __restrict__ Q2, int N) {
    __shared__ float Hs[64][HID + 4];    // stride 68: 16B-aligned rows
    const int tid = threadIdx.x;
    const int bm = blockIdx.x * 64;
    const int lane = tid & 63, w = tid >> 6;
    const int q = lane >> 4, f4 = lane & 15;
    const float4 bv4 = *(const float4*)&b1[f4 * 4];

    #pragma unroll
    for (int r = 0; r < 8; ++r) {
        const int node = bm + w * 8 + r;
        if (node >= N) break;
        const int s0 = offs[node], s1 = offs[node + 1];
        const float4 a = agg_node(Pb, sorted, s0, s1, q, f4);
        if (q == 0) {
            const float inv = 1.0f / fmaxf((float)(s1 - s0), 1.0f);
            const float4 qv = *(const float4*)&Q[(size_t)node * 64 + f4 * 4];
            float4 hv;
            hv.x = fmaxf(a.x * inv + bv4.x + qv.x, 0.f);
            hv.y = fmaxf(a.y * inv + bv4.y + qv.y, 0.f);
            hv.z = fmaxf(a.z * inv + bv4.z + qv.z, 0.f);
            hv.w = fmaxf(a.w * inv + bv4.w + qv.w, 0.f);
            *(float4*)&Hs[w * 8 + r][f4 * 4] = hv;
        }
    }
    __syncthreads();

    // gemm2: 64x64 tile, 512 threads -> 2 rows x 4 cols x 2 mats per thread
    const int tx = tid & 15, ty = tid >> 4;     // ty in [0,32)
    const int n0 = ty * 2;
    float accl[2][4] = {}, accr[2][4] = {};
    #pragma unroll 8
    for (int k = 0; k < HID; ++k) {
        float a[2];
        #pragma unroll
        for (int i = 0; i < 2; ++i) a[i] = Hs[n0 + i][k];
        const float4 blv = ((const float4*)WTl)[k * 16 + tx];
        const float4 brv = ((const float4*)WTr)[k * 16 + tx];
        const float bl[4] = {blv.x, blv.y, blv.z, blv.w};
        const float br[4] = {brv.x, brv.y, brv.z, brv.w};
        #pragma unroll
        for (int i = 0; i < 2; ++i) {
            #pragma unroll
            for (int j = 0; j < 4; ++j) {
                accl[i][j] += a[i] * bl[j];
                accr[i][j] += a[i] * br[j];
            }
        }
    }
    #pragma unroll
    for (int i = 0; i < 2; ++i) {
        int m = bm + n0 + i;
        if (m < N) {
            ushort4 pv;
            pv.x = f2bf(accl[i][0]); pv.y = f2bf(accl[i][1]);
            pv.z = f2bf(accl[i][2]); pv.w = f2bf(accl[i][3]);
            ((ushort4*)Pb2)[(size_t)m * 16 + tx] = pv;
            ((float4*)Q2)[(size_t)m * 16 + tx] =
                make_float4(accr[i][0], accr[i][1], accr[i][2], accr[i][3]);
        }
    }
}

// ---------------- P5: agg2 -> z --------------------------------------------

__global__ __launch_bounds__(256) void k_agg2(
    const unsigned short* __restrict__ Pb2, const float* __restrict__ Q2,
    const float* __restrict__ b2,
    const int* __restrict__ offs, const int* __restrict__ sorted,
    float* __restrict__ z, int N) {
    const int wid  = (blockIdx.x * 256 + threadIdx.x) >> 6;  // node
    const int lane = threadIdx.x & 63;
    const int q = lane >> 4, f4 = lane & 15;
    if (wid >= N) return;
    const int s0 = offs[wid], s1 = offs[wid + 1];
    const float4 a = agg_node(Pb2, sorted, s0, s1, q, f4);
    if (q == 0) {
        const float inv = 1.0f / fmaxf((float)(s1 - s0), 1.0f);
        const float4 qv = *(const float4*)&Q2[(size_t)wid * 64 + f4 * 4];
        const float4 bv = *(const float4*)&b2[f4 * 4];
        float4 zv;
        zv.x = a.x * inv + bv.x + qv.x;
        zv.y = a.y * inv + bv.y + qv.y;
        zv.z = a.z * inv + bv.z + qv.z;
        zv.w = a.w * inv + bv.w + qv.w;
        *(float4*)&z[(size_t)wid * 64 + f4 * 4] = zv;
    }
}

// ================================ launcher =================================

extern "C" void kernel_launch(void* const* d_in, const int* in_sizes, int n_in,
                              void* d_out, int out_size, void* d_ws, size_t ws_size,
                              hipStream_t stream) {
    const float* x   = (const float*)d_in[0];
    const int*  edge = (const int*)d_in[1];
    const float* W1l = (const float*)d_in[2];
    const float* b1l = (const float*)d_in[3];
    const float* W1r = (const float*)d_in[4];
    const float* W2l = (const float*)d_in[5];
    const float* b2l = (const float*)d_in[6];
    const float* W2r = (const float*)d_in[7];

    const int N = in_sizes[0] / INDIM;   // 40000
    const int E = in_sizes[1] / 2;       // 640000
    const int* src = edge;
    const int* dst = edge + E;

    char* w = (char*)d_ws;
    auto carve = [&](size_t bytes) {
        char* p = w; w += (bytes + 255) & ~(size_t)255; return p;
    };
    unsigned short* Pb  = (unsigned short*)carve((size_t)N * 64 * 2);
    unsigned short* Pb2 = (unsigned short*)carve((size_t)N * 64 * 2);
    float* Q    = (float*)carve((size_t)N * 64 * 4);
    float* Q2   = (float*)carve((size_t)N * 64 * 4);
    float* WT1l = (float*)carve(128 * 64 * 4);
    float* WT1r = (float*)carve(128 * 64 * 4);
    float* WT2l = (float*)carve(64 * 64 * 4);
    float* WT2r = (float*)carve(64 * 64 * 4);
    int* deg      = (int*)carve((size_t)N * 4);
    int* cursor   = (int*)carve((size_t)N * 4);
    int* sorted   = (int*)carve((size_t)E * 4);
    int* offs     = (int*)carve((size_t)(N + 1) * 4);
    int* partials = (int*)carve(256 * 4);

    float* zout = (float*)d_out;

    const int gE = (E + 255) / 256;      // 2500
    const int gT = (N + 63) / 64;        // 625 tiles
    const int gN = (N + 255) / 256;      // 157 (<= 256)

    k_prep<<<gN, 256, 0, stream>>>(W1l, W1r, W2l, W2r,
                                   WT1l, WT1r, WT2l, WT2r, deg, N);
    k_gemm1_count<<<gT, 256, 0, stream>>>(x, WT1l, WT1r, Pb, Q, dst, deg, N, E);
    k_scan_local<<<gN, 256, 0, stream>>>(deg, offs, partials, N);
    k_scan_partials<<<1, 256, 0, stream>>>(partials, offs + N, gN);
    k_scan_add<<<gN, 256, 0, stream>>>(partials, offs, cursor, N);
    k_scatter<<<gE, 256, 0, stream>>>(src, dst, cursor, sorted, E);
    k_agg1_gemm2<<<gT, 512, 0, stream>>>(Pb, Q, b1l, offs, sorted,
                                         WT2l, WT2r, Pb2, Q2, N);
    k_agg2<<<(N * 64 + 255) / 256, 256, 0, stream>>>(Pb2, Q2, b2l, offs, sorted,
                                                     zout, N);
}